// Round 5
// baseline (234.323 us; speedup 1.0000x reference)
//
#include <hip/hip_runtime.h>
#include <hip/hip_bf16.h>

// BlocDiagLinear: out[b, n*128+r] = sum_c x[b, n*128+c] * blocks[n, r, c]
// 64 GEMMs M=4096 N=128 K=128, fp32 I/O, bf16 MFMA.
// R8: deepen the DMA pipeline; get stores off the critical path.
//  R7 post-mortem (~79us, flat vs R5): vmcnt(2) at the loop top drained BOTH
//  stage(ch) and stores(ch-1) (FIFO), so every iteration waited on the HBM
//  store-ack AND ran with only 16KB/WG of loads in flight -- right at the
//  Little's-law edge for loaded-HBM latency. fillBuffer on the same trace
//  does 6.7 TB/s; we did 3.35.
//  Fixes:
//  (1) x triple-buffered (3 x 32-row x 16KB chunks): 2 chunks (32KB/WG,
//      64KB/CU) in flight through every wait.
//  (2) steady-state wait = vmcnt(8): stores(ch-1), stage(ch+1), stage(ch+2)
//      all stay outstanding; only stage(ch) is guaranteed retired.
//      Prologue ch0/ch1 -> vmcnt(4)/(6); tail ch14/ch15 -> vmcnt(6)/(4)
//      (fewer newer ops in the FIFO; derived per-iteration).
//  (3) W: unpadded XOR-swizzled bf16 (32KB, R5-verified scheme; b128 reads
//      at the 8-lane/bank-group minimum). LDS total 81920 B -> exactly
//      2 WGs/CU (163840), persistent for the whole kernel.

typedef __bf16 bf16_8 __attribute__((ext_vector_type(8)));
typedef __bf16 bf16_4 __attribute__((ext_vector_type(4)));
typedef float f32x4 __attribute__((ext_vector_type(4)));

__global__ __launch_bounds__(512, 4)
void BlocDiagLinear_kernel(const float* __restrict__ x,
                           const float* __restrict__ blocks,
                           float* __restrict__ out)
{
    __shared__ __align__(16) __bf16 wlds[128 * 128];    // 32768 B, XOR-swizzled
    __shared__ __align__(16) float  xlds[3][32 * 128];  // 3 x 16384 B

    const int bid = blockIdx.x;
    const int nb  = bid & 63;     // block index — FAST index (channel balance)
    const int own = bid >> 6;     // 0..7: owns batch rows [own*512, own*512+512)

    const int t    = threadIdx.x;
    const int lane = t & 63;
    const int w    = t >> 6;      // wave 0..7
    const int lm   = lane & 15;
    const int q    = lane >> 4;

    const int bg   = w & 1;       // batch 16-row group within 32-row chunk
    const int rb   = w >> 1;      // r-block 0..3 (32 r each)

    const int l5  = lane >> 5;    // 0/1 (row within staging pair)
    const int p31 = lane & 31;    // physical 16B granule within row

    // stage chunk `ch` into xlds[bufi]: wave w covers rows w*4..w*4+3.
    // LDS dest linear; global source granule pre-swizzled p31 ^ (row&7)
    // (rule 21: inverse of the read-side XOR).
#define STAGE(bufi, ch)                                                       \
    {                                                                         \
        _Pragma("unroll")                                                     \
        for (int i = 0; i < 2; ++i) {                                         \
            const int row  = w * 4 + i * 2 + l5;                              \
            const int gcol = (p31 ^ (row & 7)) * 4;                           \
            const float* src = x + (size_t)(own * 512 + (ch) * 32 + row) * 8192 \
                                 + nb * 128 + gcol;                           \
            __builtin_amdgcn_global_load_lds(                                 \
                (const __attribute__((address_space(1))) unsigned int*)src,   \
                (__attribute__((address_space(3))) unsigned int*)             \
                    (&xlds[bufi][(w * 4 + i * 2) * 128]),                     \
                16, 0, 0);                                                    \
        }                                                                     \
    }

    // ---- prologue: W loads to regs first, then 3 chunk DMAs ----
    const int c4 = t & 31;
    const int r0 = t >> 5;        // 0..15
    const float* wg = blocks + (size_t)nb * 16384;
    float4 wraw[8];
#pragma unroll
    for (int i = 0; i < 8; ++i)
        wraw[i] = *(const float4*)(wg + (i * 16 + r0) * 128 + c4 * 4);

    STAGE(0, 0);
    STAGE(1, 1);
    STAGE(2, 2);

    // W -> bf16, XOR-swizzled: element (row,col) at byte
    // (row*256 + col*2) ^ ((row&7)<<4)   [R5-verified]
    char* wsb = (char*)wlds;
#pragma unroll
    for (int i = 0; i < 8; ++i) {
        const int row = i * 16 + r0;
        bf16_4 bw = { (__bf16)wraw[i].x, (__bf16)wraw[i].y,
                      (__bf16)wraw[i].z, (__bf16)wraw[i].w };
        *(bf16_4*)(wsb + ((row * 256 + c4 * 8) ^ ((r0 & 7) << 4))) = bw;
    }
    asm volatile("s_waitcnt lgkmcnt(0)" ::: "memory");
    __builtin_amdgcn_sched_barrier(0);
    __builtin_amdgcn_s_barrier();   // W visible; LDS-W read-only from here

    const int swz = (lm & 7) << 4;
    int cur = 0;                    // == ch % 3; also the restage target

#pragma unroll 1
    for (int ch = 0; ch < 16; ++ch) {
        // guarantee stage(ch) retired; keep stores + 2 chunk-stages in flight
        if (ch == 0)       asm volatile("s_waitcnt vmcnt(4)" ::: "memory");
        else if (ch == 1)  asm volatile("s_waitcnt vmcnt(6)" ::: "memory");
        else if (ch == 14) asm volatile("s_waitcnt vmcnt(6)" ::: "memory");
        else if (ch == 15) asm volatile("s_waitcnt vmcnt(4)" ::: "memory");
        else               asm volatile("s_waitcnt vmcnt(8)" ::: "memory");
        __builtin_amdgcn_sched_barrier(0);
        __builtin_amdgcn_s_barrier();
        __builtin_amdgcn_sched_barrier(0);

        f32x4 acc[2];
        acc[0] = (f32x4){0.f, 0.f, 0.f, 0.f};
        acc[1] = (f32x4){0.f, 0.f, 0.f, 0.f};

        const int xrow = bg * 16 + lm;
        const int s    = xrow & 7;        // read-side XOR (matches source)
        const float* xr = &xlds[cur][xrow * 128];

#pragma unroll
        for (int kk = 0; kk < 4; ++kk) {
            const f32x4 lo = *(const f32x4*)(xr + (kk * 8 + ((q * 2 + 0) ^ s)) * 4);
            const f32x4 hi = *(const f32x4*)(xr + (kk * 8 + ((q * 2 + 1) ^ s)) * 4);
            const bf16_8 b = { (__bf16)lo.x, (__bf16)lo.y, (__bf16)lo.z, (__bf16)lo.w,
                               (__bf16)hi.x, (__bf16)hi.y, (__bf16)hi.z, (__bf16)hi.w };
#pragma unroll
            for (int rg = 0; rg < 2; ++rg) {
                const int wbyte = (((rb * 32 + rg * 16 + lm) * 256)
                                   + kk * 64 + q * 16) ^ swz;
                const bf16_8 a = *(const bf16_8*)(wsb + wbyte);
                acc[rg] = __builtin_amdgcn_mfma_f32_16x16x32_bf16(a, b, acc[rg], 0, 0, 0);
            }
        }

        // D row = q*4+reg -> r (float4 along r), col = lm -> batch row.
        float* og = out + (size_t)(own * 512 + ch * 32 + bg * 16 + lm) * 8192
                        + nb * 128 + rb * 32 + q * 4;
        *(f32x4*)(og)      = acc[0];
        *(f32x4*)(og + 16) = acc[1];

        // all waves done reading xlds[cur] before restaging it
        __builtin_amdgcn_sched_barrier(0);
        __builtin_amdgcn_s_barrier();
        __builtin_amdgcn_sched_barrier(0);

        if (ch < 13) STAGE(cur, ch + 3);
        cur = (cur == 2) ? 0 : cur + 1;
    }
#undef STAGE
}

extern "C" void kernel_launch(void* const* d_in, const int* in_sizes, int n_in,
                              void* d_out, int out_size, void* d_ws, size_t ws_size,
                              hipStream_t stream) {
    const float* x      = (const float*)d_in[0];
    const float* blocks = (const float*)d_in[1];
    float* out          = (float*)d_out;
    BlocDiagLinear_kernel<<<dim3(64 * 8), dim3(512), 0, stream>>>(x, blocks, out);
}